// Round 5
// baseline (67.193 us; speedup 1.0000x reference)
//
#include <hip/hip_runtime.h>
#include <math.h>

// out (32,64,16,2048) f32 = one_hot(ascending-sorted top-16 indices of logits+gn).
// Forward value of stop_gradient(hard-soft)+soft == hard exactly (0) / ~1ulp (1).
//
// 256-thread blocks (32 waves/CU during the store phase — matching the 7 TB/s
// rocclr fill kernel's occupancy). Hierarchical selection:
//   stage 1: wave w takes top-16 of its 512-col quarter in-wave (no barriers)
//   stage 2: all waves redundantly rank-merge the 4x16 candidates from LDS
//   store:   wave w streams output rows 4w..4w+3 (32 float4/thread) with the
//            1.0 injected inline against a wave-uniform column index.
#define K_SEL   16
#define VOCAB   2048
#define NROWS   2048   // BS(32) * D0(64)

__global__ __launch_bounds__(256) void topk_onehot_kernel(
    const float* __restrict__ logits,   // (64, 2048)
    const float* __restrict__ gn,       // (32, 64, 2048)
    float* __restrict__ out)            // (32, 64, 16, 2048)
{
    const int row  = blockIdx.x;        // row = bs*64 + d0
    const int d0   = row & 63;
    const int tid  = threadIdx.x;
    const int lane = tid & 63;
    const int w    = tid >> 6;          // wave id 0..3

    const float* grow = gn     + (size_t)row * VOCAB;
    const float* lrow = logits + (size_t)d0  * VOCAB;
    float*       orow = out    + (size_t)row * (K_SEL * VOCAB);

    // wave w owns columns [w*512, (w+1)*512); lane reg i -> col:
    //   qbase + (i>>2)*256 + lane*4 + (i&3)   (ascending in i for fixed lane)
    const int qbase = w << 9;
    float v[8];
    {
        const int cA = qbase + lane * 4;
        const int cB = qbase + 256 + lane * 4;
        const float4 gA = *reinterpret_cast<const float4*>(grow + cA);
        const float4 gB = *reinterpret_cast<const float4*>(grow + cB);
        const float4 lA = *reinterpret_cast<const float4*>(lrow + cA);
        const float4 lB = *reinterpret_cast<const float4*>(lrow + cB);
        v[0] = lA.x + gA.x; v[1] = lA.y + gA.y; v[2] = lA.z + gA.z; v[3] = lA.w + gA.w;
        v[4] = lB.x + gB.x; v[5] = lB.y + gB.y; v[6] = lB.z + gB.z; v[7] = lB.w + gB.w;
    }

    __shared__ float cv[64];      // candidate values (4 waves x 16)
    __shared__ int   ci[64];      // candidate cols
    __shared__ int   slot[4][16]; // per-wave private: selected idx by value-rank

    // stage 1: in-wave top-16 of the quarter (value desc, col asc tie-break)
    float lv = v[0]; int ls = 0;
    #pragma unroll
    for (int i = 1; i < 8; ++i) { if (v[i] > lv) { lv = v[i]; ls = i; } }

    #pragma unroll
    for (int k = 0; k < K_SEL; ++k) {
        float bv = lv;
        int   bc = qbase + ((ls >> 2) << 8) + lane * 4 + (ls & 3);
        #pragma unroll
        for (int off = 1; off < 64; off <<= 1) {
            const float ov = __shfl_xor(bv, off);
            const int   oc = __shfl_xor(bc, off);
            if (ov > bv || (ov == bv && oc < bc)) { bv = ov; bc = oc; }
        }
        if (lane == 0) { cv[w * 16 + k] = bv; ci[w * 16 + k] = bc; }
        // owner lane knocks out the winner and rescans
        if (lane == ((bc >> 2) & 63)) {
            const int s = (((bc >> 8) & 1) << 2) | (bc & 3);
            lv = -INFINITY; ls = 0;
            #pragma unroll
            for (int i = 0; i < 8; ++i) {
                if (i == s) v[i] = -INFINITY;
                if (v[i] > lv) { lv = v[i]; ls = i; }
            }
        }
    }
    __syncthreads();   // cheap: only loads/LDS outstanding, no stores yet

    // stage 2 (redundant per wave): rank lane's candidate among all 64.
    // cols globally distinct -> strict total order -> ranks unique.
    {
        const float mv = cv[lane];
        const int   mi = ci[lane];
        int rank = 0;
        #pragma unroll 8
        for (int j = 0; j < 64; ++j) {
            const float jv = cv[j]; const int ji = ci[j];
            if (jv > mv || (jv == mv && ji < mi)) ++rank;
        }
        if (rank < K_SEL) slot[w][rank] = mi;
    }
    __syncthreads();

    // idx-sort the 16 selected; wave w owns output rows 4w..4w+3
    int sA[K_SEL];
    #pragma unroll
    for (int m = 0; m < K_SEL; ++m) sA[m] = slot[w][m];
    int one[4];
    #pragma unroll
    for (int m = 0; m < K_SEL; ++m) {
        int r = 0;
        #pragma unroll
        for (int n = 0; n < K_SEL; ++n) r += (sA[n] < sA[m]) ? 1 : 0;
        #pragma unroll
        for (int q = 0; q < 4; ++q) { if (r == 4 * w + q) one[q] = sA[m]; }
    }

    // store phase: fill-kernel-shaped streaming float4 stores, one injected inline
    #pragma unroll
    for (int q = 0; q < 4; ++q) {
        float* rbase = orow + (size_t)(4 * w + q) * VOCAB;
        const int oc = one[q];
        #pragma unroll
        for (int i = 0; i < 8; ++i) {
            const int c = i * 256 + lane * 4;
            float4 a;
            a.x = (c + 0 == oc) ? 1.0f : 0.0f;
            a.y = (c + 1 == oc) ? 1.0f : 0.0f;
            a.z = (c + 2 == oc) ? 1.0f : 0.0f;
            a.w = (c + 3 == oc) ? 1.0f : 0.0f;
            *reinterpret_cast<float4*>(rbase + c) = a;
        }
    }
}

extern "C" void kernel_launch(void* const* d_in, const int* in_sizes, int n_in,
                              void* d_out, int out_size, void* d_ws, size_t ws_size,
                              hipStream_t stream) {
    const float* logits = (const float*)d_in[0];   // 64*2048
    const float* gn     = (const float*)d_in[1];   // 32*64*2048
    float* out          = (float*)d_out;           // 32*64*16*2048

    hipLaunchKernelGGL(topk_onehot_kernel, dim3(NROWS), dim3(256), 0, stream,
                       logits, gn, out);
}

// Round 6
// 64.268 us; speedup vs baseline: 1.0455x; 1.0455x over previous
//
#include <hip/hip_runtime.h>
#include <math.h>

// out (32,64,16,2048) f32 = one_hot(ascending-sorted top-16 indices of logits+gn).
// Forward value of stop_gradient(hard-soft)+soft == hard exactly (0) / ~1ulp (1).
//
// Two-kernel split, each phase in its best regime:
//   A: selection only (reads 17MB, writes 128KB of one-hot column indices to ws)
//   B: pure streaming writer (268MB of unconditional float4 stores, ones injected
//      via wave-uniform compares) — structurally identical to the ~7TB/s fill.
#define K_SEL   16
#define VOCAB   2048
#define NROWS   2048   // BS(32) * D0(64)

__global__ __launch_bounds__(64) void topk_select_kernel(
    const float* __restrict__ logits,   // (64, 2048)
    const float* __restrict__ gn,       // (32, 64, 2048)
    int* __restrict__ onecol)           // (2048, 16): col index for output row r
{
    const int row  = blockIdx.x;        // row = bs*64 + d0
    const int d0   = row & 63;
    const int lane = threadIdx.x;       // 0..63 (one wave)

    const float* grow = gn     + (size_t)row * VOCAB;
    const float* lrow = logits + (size_t)d0  * VOCAB;

    // lane owns columns c = seg*256 + lane*4 + j, seg=0..7, j=0..3
    float v[32];
    #pragma unroll
    for (int seg = 0; seg < 8; ++seg) {
        const int c = seg * 256 + lane * 4;
        const float4 g = *reinterpret_cast<const float4*>(grow + c);
        const float4 l = *reinterpret_cast<const float4*>(lrow + c);
        v[seg * 4 + 0] = l.x + g.x;
        v[seg * 4 + 1] = l.y + g.y;
        v[seg * 4 + 2] = l.z + g.z;
        v[seg * 4 + 3] = l.w + g.w;
    }

    // local argmax; ascending scan + strict '>' keeps lowest index on ties
    float lv = v[0]; int ls = 0;
    #pragma unroll
    for (int i = 1; i < 32; ++i) { if (v[i] > lv) { lv = v[i]; ls = i; } }

    int sel[K_SEL];

    // 16 rounds of wave argmax on (value desc, col asc) = lax.top_k order
    #pragma unroll
    for (int k = 0; k < K_SEL; ++k) {
        float bv = lv;
        int   bc = ((ls >> 2) << 8) + lane * 4 + (ls & 3);
        #pragma unroll
        for (int off = 1; off < 64; off <<= 1) {
            const float ov = __shfl_xor(bv, off);
            const int   oc = __shfl_xor(bc, off);
            if (ov > bv || (ov == bv && oc < bc)) { bv = ov; bc = oc; }
        }
        sel[k] = bc;  // wave-uniform after butterfly
        // owner lane knocks out the winner and rescans its local max
        if (lane == ((bc >> 2) & 63)) {
            const int s = (((bc >> 8) & 7) << 2) | (bc & 3);
            lv = -INFINITY; ls = 0;
            #pragma unroll
            for (int i = 0; i < 32; ++i) {
                if (i == s) v[i] = -INFINITY;
                if (v[i] > lv) { lv = v[i]; ls = i; }
            }
        }
    }

    // lanes 0..15: my = sel[lane] (static cndmask chain, no scratch), rank by
    // ascending index among the 16 distinct cols, one 16-lane store (64B line).
    if (lane < K_SEL) {
        int my = sel[0];
        #pragma unroll
        for (int k = 1; k < K_SEL; ++k) { if (lane == k) my = sel[k]; }
        int r = 0;
        #pragma unroll
        for (int j = 0; j < K_SEL; ++j) r += (sel[j] < my) ? 1 : 0;
        onecol[row * K_SEL + r] = my;
    }
}

__global__ __launch_bounds__(256) void onehot_write_kernel(
    const int* __restrict__ onecol,     // (2048, 16)
    float* __restrict__ out)            // (32, 64, 16, 2048)
{
    const int row = blockIdx.x;
    const int tid = threadIdx.x;
    float* orow = out + (size_t)row * (K_SEL * VOCAB);
    const int* oc = onecol + row * K_SEL;

    // 16 wave-uniform (scalarizable) loads, static-indexed into registers
    int one_[K_SEL];
    #pragma unroll
    for (int r = 0; r < K_SEL; ++r) one_[r] = oc[r];

    // 32 iterations x 16B/thread = 128KB/block of pure streaming stores.
    // All control/addresses compile-time except tid -> fill-kernel-shaped.
    #pragma unroll
    for (int i = 0; i < 32; ++i) {
        const int r     = i >> 1;
        const int cbase = ((i & 1) << 10) + tid * 4;
        const int one   = one_[r];
        float4 a;
        a.x = (cbase + 0 == one) ? 1.0f : 0.0f;
        a.y = (cbase + 1 == one) ? 1.0f : 0.0f;
        a.z = (cbase + 2 == one) ? 1.0f : 0.0f;
        a.w = (cbase + 3 == one) ? 1.0f : 0.0f;
        *reinterpret_cast<float4*>(orow + (size_t)r * VOCAB + cbase) = a;
    }
}

extern "C" void kernel_launch(void* const* d_in, const int* in_sizes, int n_in,
                              void* d_out, int out_size, void* d_ws, size_t ws_size,
                              hipStream_t stream) {
    const float* logits = (const float*)d_in[0];   // 64*2048
    const float* gn     = (const float*)d_in[1];   // 32*64*2048
    float* out          = (float*)d_out;           // 32*64*16*2048
    int*   onecol       = (int*)d_ws;              // 2048*16 ints (128KB scratch)

    hipLaunchKernelGGL(topk_select_kernel, dim3(NROWS), dim3(64), 0, stream,
                       logits, gn, onecol);
    hipLaunchKernelGGL(onehot_write_kernel, dim3(NROWS), dim3(256), 0, stream,
                       onecol, out);
}